// Round 23
// baseline (336.426 us; speedup 1.0000x reference)
//
#include <hip/hip_runtime.h>
#include <hip/hip_bf16.h>
#include <math.h>

#define NHEADS 4
#define DKH 256
#define DVH 512
#define SEQL 2048
#define NB 2
#define NTOK (NB*SEQL)     // 4096
#define DM 1024            // d_model
#define KDT 1024           // NHEADS*DKH
#define VDT 2048           // NHEADS*DVH
#define CHUNK 128
#define NCH (SEQL/CHUNK)   // 16

typedef unsigned short u16;
typedef unsigned int   u32;
typedef unsigned long long u64;
typedef __attribute__((ext_vector_type(8))) short bf16x8;
typedef __attribute__((ext_vector_type(4))) float f32x4;

__device__ inline u16 f2bf(float f) {
  __hip_bfloat16 h = __float2bfloat16(f);
  return *reinterpret_cast<u16*>(&h);
}
__device__ inline float bf2f(u16 u) {
  u32 x = ((u32)u) << 16;
  return __uint_as_float(x);
}

// async global->LDS, 16B/lane; LDS dest = wave-uniform base + lane*16 (linear).
__device__ __forceinline__ void gload16(const u16* g, u16* l) {
  __builtin_amdgcn_global_load_lds(
      (const __attribute__((address_space(1))) u32*)g,
      (__attribute__((address_space(3))) u32*)l,
      16, 0, 0);
}

__device__ inline float ls_exp(float z) {
  const float ls = (z >= 0.f) ? -log1pf(expf(-z)) : (z - log1pf(expf(z)));
  return expf(ls * 0.0625f);
}

// ---------------- fused prep: x->bf16 (blocks 0..2047) + 5 weight transposes ----
__global__ __launch_bounds__(256)
void prep_all(const float* __restrict__ x, u16* __restrict__ xb,
              const float* __restrict__ Wq, const float* __restrict__ Wk,
              const float* __restrict__ Wv, const float* __restrict__ Wg,
              const float* __restrict__ Wo, u16* __restrict__ Wall,
              u16* __restrict__ Wob)
{
  const int blk = blockIdx.x;
  if (blk < 2048) {                 // f2bf segment (no barrier)
    const int i = (blk * 256 + threadIdx.x) * 8;
    const float4 x0 = *(const float4*)&x[i];
    const float4 x1 = *(const float4*)&x[i + 4];
    int4 p;
    p.x = f2bf(x0.x) | ((u32)f2bf(x0.y) << 16);
    p.y = f2bf(x0.z) | ((u32)f2bf(x0.w) << 16);
    p.z = f2bf(x1.x) | ((u32)f2bf(x1.y) << 16);
    p.w = f2bf(x1.z) | ((u32)f2bf(x1.w) << 16);
    *(int4*)&xb[i] = p;
    return;
  }
  __shared__ float Ts[64][69];
  const int t = blk - 2048;
  const float* W; u16* Wt; int K, N, nx, ti;
  if (t < 256)       { W = Wq; Wt = Wall;                 K = 1024; N = 1024; nx = 16; ti = t; }
  else if (t < 512)  { W = Wk; Wt = Wall + 1024*1024;     K = 1024; N = 1024; nx = 16; ti = t - 256; }
  else if (t < 1024) { W = Wv; Wt = Wall + 2048*1024;     K = 1024; N = 2048; nx = 32; ti = t - 512; }
  else if (t < 1536) { W = Wg; Wt = Wall + 4096ull*1024;  K = 1024; N = 2048; nx = 32; ti = t - 1024; }
  else               { W = Wo; Wt = Wob;                  K = 2048; N = 1024; nx = 16; ti = t - 1536; }
  const int n0 = (ti % nx) * 64, k0 = (ti / nx) * 64;
  const int tx = threadIdx.x & 15, ty = threadIdx.x >> 4;
  #pragma unroll
  for (int r = 0; r < 4; ++r) {
    const int k = ty + r * 16;
    const float4 w4 = *(const float4*)&W[(size_t)(k0 + k) * N + n0 + tx * 4];
    Ts[tx*4 + 0][k] = w4.x;
    Ts[tx*4 + 1][k] = w4.y;
    Ts[tx*4 + 2][k] = w4.z;
    Ts[tx*4 + 3][k] = w4.w;
  }
  __syncthreads();
  #pragma unroll
  for (int r = 0; r < 4; ++r) {
    const int n = ty + r * 16;
    u64 pk = (u64)f2bf(Ts[n][tx*4 + 0]) | ((u64)f2bf(Ts[n][tx*4 + 1]) << 16)
           | ((u64)f2bf(Ts[n][tx*4 + 2]) << 32) | ((u64)f2bf(Ts[n][tx*4 + 3]) << 48);
    *(u64*)&Wt[(size_t)(n0 + n) * K + k0 + tx * 4] = pk;
  }
}

// ---------------- merged: projection GEMM (blocks 0..1535) + gate (1536..2047) --
// qkvg: 3-buffer counted-vmcnt pipeline (T4), swizzled LDS (rule #21).
// gate: 8 rows/block; W1/W2 thread-slices hoisted to regs (row-independent).
__global__ __launch_bounds__(256)
void qkvg_gate(const u16* __restrict__ A, const u16* __restrict__ Wall,
               u16* __restrict__ Qh, u16* __restrict__ Kh,
               u16* __restrict__ Vt, u16* __restrict__ Gh, float qscale,
               const float* __restrict__ X, const float* __restrict__ W1,
               const float* __restrict__ W2, const float* __restrict__ b2,
               float* __restrict__ EGKo)
{
  __shared__ __align__(16) u16 As[3][128 * 32];   // 24KB (gate path aliases 320B)
  __shared__ __align__(16) u16 Bs[3][128 * 32];   // 24KB
  const int tid = threadIdx.x;

  if (blockIdx.x >= 1536) {
    // ---------------- gate path: 8 rows per block ----------------
    const int rowBase = (blockIdx.x - 1536) * 8;
    float* Us   = (float*)&As[0][0];      // 16 floats
    float* wred = Us + 16;                // 4x16 floats

    // row-independent weight slices -> registers (amortized over 8 rows)
    float4 w1r[4][4];                     // k = 4*tid+u, n = 4g..4g+3
    #pragma unroll
    for (int u = 0; u < 4; ++u) {
      const int k = tid * 4 + u;
      #pragma unroll
      for (int g = 0; g < 4; ++g)
        w1r[u][g] = *(const float4*)&W1[k*16 + g*4];
    }
    float4 w2r[16];                       // col slice d0..d0+3
    const int d0 = tid << 2;
    #pragma unroll
    for (int r = 0; r < 16; ++r)
      w2r[r] = *(const float4*)&W2[r * 1024 + d0];
    const float4 bb = *(const float4*)&b2[d0];

    for (int rr = 0; rr < 8; ++rr) {
      const int row = rowBase + rr;
      float p[16];
      #pragma unroll
      for (int n = 0; n < 16; ++n) p[n] = 0.f;
      const float4 x4 = *(const float4*)&X[(size_t)row * 1024 + tid * 4];
      const float xv[4] = {x4.x, x4.y, x4.z, x4.w};
      #pragma unroll
      for (int u = 0; u < 4; ++u) {
        p[0]  += xv[u]*w1r[u][0].x; p[1]  += xv[u]*w1r[u][0].y;
        p[2]  += xv[u]*w1r[u][0].z; p[3]  += xv[u]*w1r[u][0].w;
        p[4]  += xv[u]*w1r[u][1].x; p[5]  += xv[u]*w1r[u][1].y;
        p[6]  += xv[u]*w1r[u][1].z; p[7]  += xv[u]*w1r[u][1].w;
        p[8]  += xv[u]*w1r[u][2].x; p[9]  += xv[u]*w1r[u][2].y;
        p[10] += xv[u]*w1r[u][2].z; p[11] += xv[u]*w1r[u][2].w;
        p[12] += xv[u]*w1r[u][3].x; p[13] += xv[u]*w1r[u][3].y;
        p[14] += xv[u]*w1r[u][3].z; p[15] += xv[u]*w1r[u][3].w;
      }
      #pragma unroll
      for (int n = 0; n < 16; ++n) {
        #pragma unroll
        for (int off = 32; off > 0; off >>= 1)
          p[n] += __shfl_down(p[n], off);
      }
      if ((tid & 63) == 0) {
        #pragma unroll
        for (int n = 0; n < 16; ++n) wred[(tid >> 6) * 16 + n] = p[n];
      }
      __syncthreads();
      if (tid < 16)
        Us[tid] = wred[tid] + wred[16 + tid] + wred[32 + tid] + wred[48 + tid];
      __syncthreads();

      float4 z = bb;
      #pragma unroll
      for (int r = 0; r < 16; ++r) {
        const float u = Us[r];
        z.x += u * w2r[r].x; z.y += u * w2r[r].y;
        z.z += u * w2r[r].z; z.w += u * w2r[r].w;
      }
      float4 e = make_float4(ls_exp(z.x), ls_exp(z.y), ls_exp(z.z), ls_exp(z.w));
      *(float4*)&EGKo[(size_t)row * 1024 + d0] = e;
      __syncthreads();   // Us/wred reused next row
    }
    return;
  }

  // ---------------- qkvg path ----------------
  const int lane = tid & 63, wave = tid >> 6;
  const int wr = wave >> 1, wc = wave & 1;
  const int l15 = lane & 15, l4 = lane >> 4;
  const int bx = blockIdx.x % 48;
  const int bm = (blockIdx.x / 48) * 128, bn = bx * 128;

  f32x4 acc[4][4];
  #pragma unroll
  for (int i = 0; i < 4; ++i)
    #pragma unroll
    for (int j = 0; j < 4; ++j)
      acc[i][j] = (f32x4){0.f, 0.f, 0.f, 0.f};

  const int sRow = wave * 32 + (lane >> 2);
  const int sswz = (lane >> 3) & 3;                  // ((sRow>>1)&3)
  const int sCol = ((lane & 3) ^ sswz) * 8;          // swizzled global source col
  const int rswz = (l15 >> 1) & 3;
  const int ru = (l4 ^ rswz) * 8;                    // physical unit for frag reads
  const u16* Ag0 = &A   [(size_t)(bm + sRow) * DM + sCol];
  const u16* Ag1 = &A   [(size_t)(bm + sRow + 16) * DM + sCol];
  const u16* Bg0 = &Wall[(size_t)(bn + sRow) * DM + sCol];
  const u16* Bg1 = &Wall[(size_t)(bn + sRow + 16) * DM + sCol];
  const int lb0 = (wave * 32) * 32, lb1 = (wave * 32 + 16) * 32;

  // prologue: tiles 0 and 1 in flight (8 outstanding loads/wave)
  gload16(Ag0, &As[0][lb0]);
  gload16(Ag1, &As[0][lb1]);
  gload16(Bg0, &Bs[0][lb0]);
  gload16(Bg1, &Bs[0][lb1]);
  gload16(Ag0 + 32, &As[1][lb0]);
  gload16(Ag1 + 32, &As[1][lb1]);
  gload16(Bg0 + 32, &Bs[1][lb0]);
  gload16(Bg1 + 32, &Bs[1][lb1]);

  for (int k0 = 0; k0 < DM; k0 += 32) {
    const int cur = (k0 >> 5) % 3;
    // retire the oldest tile's 4 loads; keep the newest 4 in flight
    if (k0 + 64 < DM) asm volatile("s_waitcnt vmcnt(4)" ::: "memory");
    else              asm volatile("s_waitcnt vmcnt(0)" ::: "memory");
    __builtin_amdgcn_s_barrier();    // raw barrier: no vmcnt(0) drain
    if (k0 + 64 < DM) {              // issue tile k+2 (buffer read last in iter k-1)
      const int nxt = ((k0 >> 5) + 2) % 3;
      gload16(Ag0 + k0 + 64, &As[nxt][lb0]);
      gload16(Ag1 + k0 + 64, &As[nxt][lb1]);
      gload16(Bg0 + k0 + 64, &Bs[nxt][lb0]);
      gload16(Bg1 + k0 + 64, &Bs[nxt][lb1]);
    }
    bf16x8 af[4], bfv[4];
    #pragma unroll
    for (int mi = 0; mi < 4; ++mi)
      af[mi] = *(const bf16x8*)&As[cur][(wr*64 + mi*16 + l15) * 32 + ru];
    #pragma unroll
    for (int ni = 0; ni < 4; ++ni)
      bfv[ni] = *(const bf16x8*)&Bs[cur][(wc*64 + ni*16 + l15) * 32 + ru];
    #pragma unroll
    for (int mi = 0; mi < 4; ++mi)
      #pragma unroll
      for (int ni = 0; ni < 4; ++ni)
        acc[mi][ni] = __builtin_amdgcn_mfma_f32_16x16x32_bf16(af[mi], bfv[ni], acc[mi][ni], 0, 0, 0);
  }

  // per-segment bf16 epilogue (bx uniform per block)
  if (bx < 8) {              // Q cols [0,1024), scaled
    #pragma unroll
    for (int mi = 0; mi < 4; ++mi)
      #pragma unroll
      for (int ni = 0; ni < 4; ++ni) {
        const int col = bn + wc*64 + ni*16 + l15;
        #pragma unroll
        for (int r = 0; r < 4; ++r)
          Qh[(size_t)(bm + wr*64 + mi*16 + l4*4 + r) * 1024 + col] = f2bf(acc[mi][ni][r] * qscale);
      }
  } else if (bx < 16) {      // K cols [1024,2048)
    #pragma unroll
    for (int mi = 0; mi < 4; ++mi)
      #pragma unroll
      for (int ni = 0; ni < 4; ++ni) {
        const int col = bn - 1024 + wc*64 + ni*16 + l15;
        #pragma unroll
        for (int r = 0; r < 4; ++r)
          Kh[(size_t)(bm + wr*64 + mi*16 + l4*4 + r) * 1024 + col] = f2bf(acc[mi][ni][r]);
      }
  } else if (bx < 32) {      // V cols [2048,4096) -> transposed bf16 Vt
    #pragma unroll
    for (int mi = 0; mi < 4; ++mi) {
      const int row0 = bm + wr*64 + mi*16 + l4*4;   // token
      const int b = row0 >> 11, l = row0 & 2047;
      #pragma unroll
      for (int ni = 0; ni < 4; ++ni) {
        const int colV = bn - 2048 + wc*64 + ni*16 + l15;   // h*512 + dv
        const int h = colV >> 9, dv = colV & 511;
        u64 pk = (u64)f2bf(acc[mi][ni][0]) | ((u64)f2bf(acc[mi][ni][1]) << 16)
               | ((u64)f2bf(acc[mi][ni][2]) << 32) | ((u64)f2bf(acc[mi][ni][3]) << 48);
        *(u64*)&Vt[((size_t)((b*4 + h)*512 + dv)) * SEQL + l] = pk;
      }
    }
  } else {                   // G cols [4096,6144)
    #pragma unroll
    for (int mi = 0; mi < 4; ++mi)
      #pragma unroll
      for (int ni = 0; ni < 4; ++ni) {
        const int col = bn - 4096 + wc*64 + ni*16 + l15;
        #pragma unroll
        for (int r = 0; r < 4; ++r)
          Gh[(size_t)(bm + wr*64 + mi*16 + l4*4 + r) * 2048 + col] = f2bf(acc[mi][ni][r]);
      }
  }
}

// ---------------- generic bf16 GEMM: 3-buffer COUNTED-VMCNT pipeline, fp32 C ----
__global__ __launch_bounds__(256)
void gemm_bf16(const u16* __restrict__ A, const u16* __restrict__ Bt,
               float* __restrict__ C, int M, int N, int K, float scale)
{
  __shared__ __align__(16) u16 As[3][128 * 32];
  __shared__ __align__(16) u16 Bs[3][128 * 32];
  const int tid = threadIdx.x;
  const int lane = tid & 63, wave = tid >> 6;
  const int wr = wave >> 1, wc = wave & 1;
  const int l15 = lane & 15, l4 = lane >> 4;
  const int bm = blockIdx.y * 128, bn = blockIdx.x * 128;

  f32x4 acc[4][4];
  #pragma unroll
  for (int i = 0; i < 4; ++i)
    #pragma unroll
    for (int j = 0; j < 4; ++j)
      acc[i][j] = (f32x4){0.f, 0.f, 0.f, 0.f};

  const int sRow = wave * 32 + (lane >> 2);
  const int sswz = (lane >> 3) & 3;
  const int sCol = ((lane & 3) ^ sswz) * 8;
  const int rswz = (l15 >> 1) & 3;
  const int ru = (l4 ^ rswz) * 8;
  const u16* Ag0 = &A [(size_t)(bm + sRow) * K + sCol];
  const u16* Ag1 = &A [(size_t)(bm + sRow + 16) * K + sCol];
  const u16* Bg0 = &Bt[(size_t)(bn + sRow) * K + sCol];
  const u16* Bg1 = &Bt[(size_t)(bn + sRow + 16) * K + sCol];
  const int lb0 = (wave * 32) * 32, lb1 = (wave * 32 + 16) * 32;

  // prologue: tiles 0 and 1 in flight
  gload16(Ag0, &As[0][lb0]);
  gload16(Ag1, &As[0][lb1]);
  gload16(Bg0, &Bs[0][lb0]);
  gload16(Bg1, &Bs[0][lb1]);
  gload16(Ag0 + 32, &As[1][lb0]);
  gload16(Ag1 + 32, &As[1][lb1]);
  gload16(Bg0 + 32, &Bs[1][lb0]);
  gload16(Bg1 + 32, &Bs[1][lb1]);

  for (int k0 = 0; k0 < K; k0 += 32) {
    const int cur = (k0 >> 5) % 3;
    if (k0 + 64 < K) asm volatile("s_waitcnt vmcnt(4)" ::: "memory");
    else             asm volatile("s_waitcnt vmcnt(0)" ::: "memory");
    __builtin_amdgcn_s_barrier();
    if (k0 + 64 < K) {
      const int nxt = ((k0 >> 5) + 2) % 3;
      gload16(Ag0 + k0 + 64, &As[nxt][lb0]);
      gload16(Ag1 + k0 + 64, &As[nxt][lb1]);
      gload16(Bg0 + k0 + 64, &Bs[nxt][lb0]);
      gload16(Bg1 + k0 + 64, &Bs[nxt][lb1]);
    }
    bf16x8 af[4], bfv[4];
    #pragma unroll
    for (int mi = 0; mi < 4; ++mi)
      af[mi] = *(const bf16x8*)&As[cur][(wr*64 + mi*16 + l15) * 32 + ru];
    #pragma unroll
    for (int ni = 0; ni < 4; ++ni)
      bfv[ni] = *(const bf16x8*)&Bs[cur][(wc*64 + ni*16 + l15) * 32 + ru];
    #pragma unroll
    for (int mi = 0; mi < 4; ++mi)
      #pragma unroll
      for (int ni = 0; ni < 4; ++ni)
        acc[mi][ni] = __builtin_amdgcn_mfma_f32_16x16x32_bf16(af[mi], bfv[ni], acc[mi][ni], 0, 0, 0);
  }

  #pragma unroll
  for (int mi = 0; mi < 4; ++mi)
    #pragma unroll
    for (int ni = 0; ni < 4; ++ni) {
      const int col = bn + wc*64 + ni*16 + l15;
      #pragma unroll
      for (int r = 0; r < 4; ++r) {
        const int row = bm + wr*64 + mi*16 + l4*4 + r;
        C[(size_t)row * N + col] = acc[mi][ni][r] * scale;
      }
    }
}

// ---------------- chunk_prep (bf16 in): qt=q*Lam, kt=k/Lam, kh=kt*LamC ----------
__global__ __launch_bounds__(256)
void chunk_prep(const u16* __restrict__ Qh, const u16* __restrict__ Kh,
                const float* __restrict__ EG, u16* __restrict__ qtb,
                u16* __restrict__ ktb, u16* __restrict__ khb,
                float* __restrict__ lamC)
{
  const int j = blockIdx.x;
  const int bh = blockIdx.y;
  const int b = bh >> 2, h = bh & 3;
  const int tid = threadIdx.x;   // dk lane
  const size_t base = ((size_t)(b * SEQL + j * CHUNK)) * KDT + h * DKH + tid;
  float cum = 1.f;
  for (int t = 0; t < CHUNK; t += 4) {
    const size_t i0 = base + (size_t)t * KDT;
    float d[4], q[4], k[4];
    #pragma unroll
    for (int u = 0; u < 4; ++u) {
      d[u] = EG[i0 + (size_t)u * KDT];
      q[u] = bf2f(Qh[i0 + (size_t)u * KDT]);
      k[u] = bf2f(Kh[i0 + (size_t)u * KDT]);
    }
    #pragma unroll
    for (int u = 0; u < 4; ++u) {
      cum *= d[u];
      qtb[i0 + (size_t)u * KDT] = f2bf(q[u] * cum);
      ktb[i0 + (size_t)u * KDT] = f2bf(k[u] / cum);
    }
  }
  lamC[(bh * NCH + j) * 256 + tid] = cum;
  for (int t = 0; t < CHUNK; t += 4) {
    const size_t i0 = base + (size_t)t * KDT;
    u16 kt4[4];
    #pragma unroll
    for (int u = 0; u < 4; ++u) kt4[u] = ktb[i0 + (size_t)u * KDT];
    #pragma unroll
    for (int u = 0; u < 4; ++u)
      khb[i0 + (size_t)u * KDT] = f2bf(bf2f(kt4[u]) * cum);
  }
}

// ---------------- gla_pstate_mfma: P^T[dv][dk] = Vt_j @ kh_j (MFMA), bf16 P out -
__global__ __launch_bounds__(256)
void gla_pstate_mfma(const u16* __restrict__ kh, const u16* __restrict__ Vt,
                     u16* __restrict__ P)
{
  const int mb = blockIdx.x, nb = blockIdx.y, jc = blockIdx.z;
  const int bh = jc >> 4, j = jc & 15;
  const int b = bh >> 2, h = bh & 3;
  const int tid = threadIdx.x;
  const int lane = tid & 63, wave = tid >> 6;
  const int wr = wave >> 1, wc = wave & 1;
  const int l15 = lane & 15, l4 = lane >> 4;
  const int tok0 = b * SEQL + j * CHUNK;

  __shared__ __align__(16) u16 Al[128 * 40];   // Vt [dv][t]
  __shared__ __align__(16) u16 Blt[128 * 40];  // kh^T [dk][t]

  f32x4 acc[4][4];
  #pragma unroll
  for (int i = 0; i < 4; ++i)
    #pragma unroll
    for (int jj = 0; jj < 4; ++jj) acc[i][jj] = (f32x4){0.f,0.f,0.f,0.f};

  for (int kt0 = 0; kt0 < CHUNK; kt0 += 32) {
    {
      const int srow = tid >> 2, scol = (tid & 3) * 8;
      *(int4*)&Al[(srow)    * 40 + scol] =
        *(const int4*)&Vt[((size_t)(bh*512 + mb*128 + srow))    * SEQL + j*CHUNK + kt0 + scol];
      *(int4*)&Al[(64+srow) * 40 + scol] =
        *(const int4*)&Vt[((size_t)(bh*512 + mb*128 + 64+srow)) * SEQL + j*CHUNK + kt0 + scol];
    }
    {
      const int t = tid & 31;
      #pragma unroll
      for (int i = 0; i < 2; ++i) {
        const int dkg = (tid >> 5) * 16 + i * 8;
        int4 v = *(const int4*)&kh[(size_t)(tok0 + kt0 + t) * KDT + h*DKH + nb*128 + dkg];
        const u16* pv = (const u16*)&v;
        #pragma unroll
        for (int u = 0; u < 8; ++u) Blt[(dkg + u)*40 + t] = pv[u];
      }
    }
    __syncthreads();
    bf16x8 af[4], bv[4];
    #pragma unroll
    for (int mi = 0; mi < 4; ++mi)
      af[mi] = *(const bf16x8*)&Al[(wr*64 + mi*16 + l15)*40 + l4*8];
    #pragma unroll
    for (int ni = 0; ni < 4; ++ni)
      bv[ni] = *(const bf16x8*)&Blt[(wc*64 + ni*16 + l15)*40 + l4*8];
    #pragma unroll
    for (int mi = 0; mi < 4; ++mi)
      #pragma unroll
      for (int ni = 0; ni < 4; ++ni)
        acc[mi][ni] = __builtin_amdgcn_mfma_f32_16x16x32_bf16(af[mi], bv[ni], acc[mi][ni], 0, 0, 0);
    __syncthreads();
  }

  #pragma unroll
  for (int mi = 0; mi < 4; ++mi)
    #pragma unroll
    for (int ni = 0; ni < 4; ++ni) {
      const int col = nb*128 + wc*64 + ni*16 + l15;   // dk
      #pragma unroll
      for (int r = 0; r < 4; ++r) {
        const int row = mb*128 + wr*64 + mi*16 + l4*4 + r;  // dv
        P[(size_t)jc * 131072 + (size_t)row * 256 + col] = f2bf(acc[mi][ni][r]);
      }
    }
}

// ---------------- gla_sscan: S^T recurrence, bf16 P in, bf16 SjT out ------------
__global__ __launch_bounds__(256)
void gla_sscan(const u16* __restrict__ P, const float* __restrict__ lamC,
               u16* __restrict__ SjT)
{
  const int bh = blockIdx.y;
  const int e0 = blockIdx.x * 1024 + threadIdx.x * 4;
  const int dv = e0 >> 8, dk = e0 & 255;
  float4 S = make_float4(0.f, 0.f, 0.f, 0.f);
  for (int j = 0; j < NCH; ++j) {
    const size_t cb = (size_t)(bh * NCH + j);
    const float4 lam = *(const float4*)&lamC[cb * 256 + dk];
    const size_t idx = cb * 131072 + (size_t)dv * 256 + dk;
    const u64 pkin = *(const u64*)&P[idx];
    const float t0 = bf2f((u16)(pkin       & 0xffff));
    const float t1 = bf2f((u16)((pkin>>16) & 0xffff));
    const float t2 = bf2f((u16)((pkin>>32) & 0xffff));
    const float t3 = bf2f((u16)((pkin>>48) & 0xffff));
    u64 pk = (u64)f2bf(S.x) | ((u64)f2bf(S.y) << 16)
           | ((u64)f2bf(S.z) << 32) | ((u64)f2bf(S.w) << 48);
    *(u64*)&SjT[idx] = pk;
    S.x = lam.x * S.x + t0;
    S.y = lam.y * S.y + t1;
    S.z = lam.z * S.z + t2;
    S.w = lam.w * S.w + t3;
  }
}

// ---------------- fused gla core: O(bf16) = tril(qt@kt^T)@V + qt@S_j ------------
__global__ __launch_bounds__(256)
void gla_intra_mfma(const u16* __restrict__ qt, const u16* __restrict__ kt,
                    const u16* __restrict__ Vt, const u16* __restrict__ SjT,
                    u16* __restrict__ O)
{
  const int half = blockIdx.x;
  const int j    = blockIdx.y;
  const int bh   = blockIdx.z;
  const int b = bh >> 2, h = bh & 3;
  const int tid = threadIdx.x;
  const int lane = tid & 63, wave = tid >> 6;
  const int wr = wave >> 1, wc = wave & 1;
  const int l15 = lane & 15, l4 = lane >> 4;
  const int tok0 = b * SEQL + j * CHUNK;

  __shared__ __align__(16) u16 Pl[128 * 136];    // masked P bf16 [t][s]
  __shared__ __align__(16) u16 stg[128 * 136];   // union staging (17408 u16)
  u16* As  = stg;                  // [128][40] qt
  u16* Bs0 = stg + 128 * 40;       // [128][40] kt / SjT-dt0
  u16* Bs1 = stg + 2 * 128 * 40;   // [128][40] SjT-dt1

  const size_t qkBase = (size_t)tok0 * KDT + h * DKH;
  const size_t sjBase = (size_t)(bh * NCH + j) * 131072;

  const int srow = tid >> 2;
  const int scol = (tid & 3) * 8;

  // ---- QK^T (K=256), reg prefetch ----
  f32x4 acc[4][4];
  #pragma unroll
  for (int i = 0; i < 4; ++i)
    #pragma unroll
    for (int jj = 0; jj < 4; ++jj) acc[i][jj] = (f32x4){0.f,0.f,0.f,0.f};

  int4 ra0 = *(const int4*)&qt[qkBase + (size_t)srow      * KDT + scol];
  int4 ra1 = *(const int4*)&qt[qkBase + (size_t)(64+srow) * KDT + scol];
  int4 rb0 = *(const int4*)&kt[qkBase + (size_t)srow      * KDT + scol];
  int4 rb1 = *(const int4*)&kt[qkBase + (size_t)(64+srow) * KDT + scol];

  for (int dk0 = 0; dk0 < DKH; dk0 += 32) {
    __syncthreads();
    *(int4*)&As [(srow)    * 40 + scol] = ra0;
    *(int4*)&As [(64+srow) * 40 + scol] = ra1;
    *(int4*)&Bs0[(srow)    * 40 + scol] = rb0;
    *(int4*)&Bs0[(64+srow) * 40 + scol] = rb1;
    __syncthreads();
    if (dk0 + 32 < DKH) {
      ra0 = *(const int4*)&qt[qkBase + (size_t)srow      * KDT + dk0 + 32 + scol];
      ra1 = *(const int4*)&qt[qkBase + (size_t)(64+srow) * KDT + dk0 + 32 + scol];
      rb0 = *(const int4*)&kt[qkBase + (size_t)srow      * KDT + dk0 + 32 + scol];
      rb1 = *(const int4*)&kt[qkBase + (size_t)(64+srow) * KDT + dk0 + 32 + scol];
    }
    if (wave != 1) {   // wave 1 = (wr0,wc1): rows 0-63 x cols 64-127, all masked
      bf16x8 af[4], bv[4];
      #pragma unroll
      for (int mi = 0; mi < 4; ++mi)
        af[mi] = *(const bf16x8*)&As[(wr*64 + mi*16 + l15) * 40 + l4*8];
      #pragma unroll
      for (int ni = 0; ni < 4; ++ni)
        bv[ni] = *(const bf16x8*)&Bs0[(wc*64 + ni*16 + l15) * 40 + l4*8];
      #pragma unroll
      for (int mi = 0; mi < 4; ++mi)
        #pragma unroll
        for (int ni = 0; ni < 4; ++ni)
          acc[mi][ni] = __builtin_amdgcn_mfma_f32_16x16x32_bf16(af[mi], bv[ni], acc[mi][ni], 0, 0, 0);
    }
  }
  __syncthreads();

  // mask -> Pl bf16 [t][s]  (wave 1 writes zeros)
  #pragma unroll
  for (int mi = 0; mi < 4; ++mi)
    #pragma unroll
    for (int ni = 0; ni < 4; ++ni) {
      const int s = wc*64 + ni*16 + l15;
      #pragma unroll
      for (int r = 0; r < 4; ++r) {
        const int t = wr*64 + mi*16 + l4*4 + r;
        Pl[t*136 + s] = (s <= t) ? f2bf(acc[mi][ni][r]) : (u16)0;
      }
    }
  __syncthreads();

  // ---- inter for BOTH dt tiles in one k-loop: qt staged once ----
  const int dv0 = half*256;
  const int dv1 = half*256 + 128;
  f32x4 acc2[2][4][4];
  #pragma unroll
  for (int d = 0; d < 2; ++d)
    #pragma unroll
    for (int i = 0; i < 4; ++i)
      #pragma unroll
      for (int jj = 0; jj < 4; ++jj) acc2[d][i][jj] = (f32x4){0.f,0.f,0.f,0.f};

  int4 ia0 = *(const int4*)&qt [qkBase + (size_t)srow      * KDT + scol];
  int4 ia1 = *(const int4*)&qt [qkBase + (size_t)(64+srow) * KDT + scol];
  int4 ib0 = *(const int4*)&SjT[sjBase + (size_t)(dv0 + srow)      * 256 + scol];
  int4 ib1 = *(const int4*)&SjT[sjBase + (size_t)(dv0 + 64 + srow) * 256 + scol];
  int4 ic0 = *(const int4*)&SjT[sjBase + (size_t)(dv1 + srow)      * 256 + scol];
  int4 ic1 = *(const int4*)&SjT[sjBase + (size_t)(dv1 + 64 + srow) * 256 + scol];

  for (int k0 = 0; k0 < DKH; k0 += 32) {
    __syncthreads();
    *(int4*)&As [(srow)    * 40 + scol] = ia0;
    *(int4*)&As [(64+srow) * 40 + scol] = ia1;
    *(int4*)&Bs0[(srow)    * 40 + scol] = ib0;
    *(int4*)&Bs0[(64+srow) * 40 + scol] = ib1;
    *(int4*)&Bs1[(srow)    * 40 + scol] = ic0;
    *(int4*)&Bs1[(64+srow) * 40 + scol] = ic1;
    __syncthreads();
    if (k0 + 32 < DKH) {
      ia0 = *(const int4*)&qt [qkBase + (size_t)srow      * KDT + k0 + 32 + scol];
      ia1 = *(const int4*)&qt [qkBase + (size_t)(64+srow) * KDT + k0 + 32 + scol];
      ib0 = *(const int4*)&SjT[sjBase + (size_t)(dv0 + srow)      * 256 + k0 + 32 + scol];
      ib1 = *(const int4*)&SjT[sjBase + (size_t)(dv0 + 64 + srow) * 256 + k0 + 32 + scol];
      ic0 = *(const int4*)&SjT[sjBase + (size_t)(dv1 + srow)      * 256 + k0 + 32 + scol];
      ic1 = *(const int4*)&SjT[sjBase + (size_t)(dv1 + 64 + srow) * 256 + k0 + 32 + scol];
    }
    bf16x8 af[4], bv0[4], bv1[4];
    #pragma unroll
    for (int mi = 0; mi < 4; ++mi)
      af[mi] = *(const bf16x8*)&As[(wr*64 + mi*16 + l15) * 40 + l4*8];
    #pragma unroll
    for (int ni = 0; ni < 4; ++ni) {
      bv0[ni] = *(const bf16x8*)&Bs0[(wc*64 + ni*16 + l15) * 40 + l4*8];
      bv1[ni] = *(const bf16x8*)&Bs1[(wc*64 + ni*16 + l15) * 40 + l4*8];
    }
    #pragma unroll
    for (int mi = 0; mi < 4; ++mi)
      #pragma unroll
      for (int ni = 0; ni < 4; ++ni) {
        acc2[0][mi][ni] = __builtin_amdgcn_mfma_f32_16x16x32_bf16(af[mi], bv0[ni], acc2[0][mi][ni], 0, 0, 0);
        acc2[1][mi][ni] = __builtin_amdgcn_mfma_f32_16x16x32_bf16(af[mi], bv1[ni], acc2[1][mi][ni], 0, 0, 0);
      }
  }
  __syncthreads();

  // ---- PV per dt: stage V tile then 16 MFMA, single bf16 O write ----
  for (int dt = 0; dt < 2; ++dt) {
    const int dvBase = half*256 + dt*128;
    #pragma unroll
    for (int i = 0; i < 8; ++i) {
      const int row = i*16 + (tid >> 4);
      const int col8 = (tid & 15) * 8;
      *(int4*)&stg[row*136 + col8] =
        *(const int4*)&Vt[((size_t)(bh*512 + dvBase + row)) * SEQL + j*CHUNK + col8];
    }
    __syncthreads();
    #pragma unroll
    for (int ks = 0; ks < 4; ++ks) {
      bf16x8 af2[4], bv2[4];
      #pragma unroll
      for (int mi = 0; mi < 4; ++mi)
        af2[mi] = *(const bf16x8*)&Pl[(wr*64 + mi*16 + l15)*136 + ks*32 + l4*8];
      #pragma unroll
      for (int ni = 0; ni < 4; ++ni)
        bv2[ni] = *(const bf16x8*)&stg[(wc*64 + ni*16 + l15)*136 + ks*32 + l4*8];
      #pragma unroll
      for (int mi = 0; mi < 4; ++mi)
        #pragma unroll
        for (int ni = 0; ni < 4; ++ni)
          acc2[dt][mi][ni] = __builtin_amdgcn_mfma_f32_16x16x32_bf16(af2[mi], bv2[ni], acc2[dt][mi][ni], 0, 0, 0);
    }
    #pragma unroll
    for (int mi = 0; mi < 4; ++mi)
      #pragma unroll
      for (int ni = 0; ni < 4; ++ni) {
        const int col = h*DVH + dvBase + wc*64 + ni*16 + l15;
        #pragma unroll
        for (int r = 0; r < 4; ++r) {
          const int row = tok0 + wr*64 + mi*16 + l4*4 + r;
          O[(size_t)row * VDT + col] = f2bf(acc2[dt][mi][ni][r]);
        }
      }
    __syncthreads();
  }
}

// ---------------- epilogue: Y(bf16) = RMSNorm(o)*w * silu(g), bf16 O,G ----------
__global__ __launch_bounds__(256)
void epilogue(const u16* __restrict__ O, const u16* __restrict__ G,
              const float* __restrict__ w, u16* __restrict__ Y)
{
  const int row = blockIdx.x;
  const int tid = threadIdx.x;
  __shared__ float sred[4];
  for (int h = 0; h < NHEADS; ++h) {
    const size_t base = (size_t)row * VDT + h * DVH;
    const u32 o2p = *(const u32*)&O[base + tid * 2];
    const float ox = bf2f((u16)(o2p & 0xffff));
    const float oy = bf2f((u16)(o2p >> 16));
    float ss = ox * ox + oy * oy;
    #pragma unroll
    for (int off = 32; off > 0; off >>= 1) ss += __shfl_down(ss, off);
    if ((tid & 63) == 0) sred[tid >> 6] = ss;
    __syncthreads();
    const float tot = sred[0] + sred[1] + sred[2] + sred[3];
    const float rs = rsqrtf(tot * (1.f / DVH) + 1e-5f);
    const u32 g2p = *(const u32*)&G[base + tid * 2];
    const float gx = bf2f((u16)(g2p & 0xffff));
    const float gy = bf2f((u16)(g2p >> 16));
    const float2 w2 = *(const float2*)&w[tid * 2];
    const float y0 = ox * rs * w2.x * gx / (1.f + expf(-gx));
    const float y1 = oy * rs * w2.y * gy / (1.f + expf(-gy));
    const u32 pk = (u32)f2bf(y0) | ((u32)f2bf(y1) << 16);
    *(u32*)&Y[base + tid * 2] = pk;
    __syncthreads();
  }
}

extern "C" void kernel_launch(void* const* d_in, const int* in_sizes, int n_in,
                              void* d_out, int out_size, void* d_ws, size_t ws_size,
                              hipStream_t stream)
{
  const float* x    = (const float*)d_in[0];
  const float* Wq   = (const float*)d_in[1];
  const float* Wk   = (const float*)d_in[2];
  const float* Wv   = (const float*)d_in[3];
  const float* Wg   = (const float*)d_in[4];
  const float* gw1  = (const float*)d_in[5];
  const float* gw2  = (const float*)d_in[6];
  const float* gb2  = (const float*)d_in[7];
  const float* gnw  = (const float*)d_in[8];
  const float* Wo   = (const float*)d_in[9];
  float* out = (float*)d_out;

  // ---- workspace layout (float-slot offsets; liveness documented) ----
  float* ws = (float*)d_ws;
  const size_t M = 1024ull * 1024ull;
  u16*   Qbh  = (u16*)(ws);         // [0,2M)   bf16 Q; dead after chunk_prep
  u16*   Kbh  = (u16*)(ws + 2*M);   // [2M,4M)  bf16 K; dead after chunk_prep
  float* EGK  = ws + 4*M;           // [4M,8M)  fp32 decay; dead after chunk_prep
  u16*   Vtb  = (u16*)(ws + 8*M);   // [8M,12M) bf16 Vt; LIVE until gla_intra done
  u16*   qtb  = (u16*)(ws + 12*M);  // [12M,14M) live until gla_intra
  u16*   ktb  = (u16*)(ws + 14*M);  // [14M,16M) live until gla_intra
  u16*   Gbh  = (u16*)(ws + 16*M);  // [16M,20M) bf16 G; live until epilogue
  u16*   Obh  = (u16*)(ws + 20*M);  // [20M,24M) bf16 O
  u16*   Pjb  = (u16*)(ws + 28*M);  // [28M,36M) bf16 P^T; dead after sscan
  float* lamC = ws + 44*M;          // [44M, +32K)
  u16*   khb  = (u16*)(ws + 45*M);  // [45M,47M) dead after gla_pstate
  u16*   xb   = (u16*)(ws + 47*M);  // [47M,49M) dead after qkvg_gate
  u16*   Wallb= (u16*)(ws + 49*M);  // [49M,52M) dead after qkvg_gate
  u16*   Wob  = (u16*)(ws + 52*M);  // [52M,53M) live until final gemm
  u16*   SjTb = (u16*)(ws + 53*M);  // [53M,61M) 32MB; fresh region (no aliasing)
  u16*   Y2b  = (u16*)(ws);         // [0,4M) reuses Qbh+Kbh after chunk_prep

  const float qscale = 0.0625f;     // DK^-0.5

  prep_all<<<4096, 256, 0, stream>>>(x, xb, Wq, Wk, Wv, Wg, Wo, Wallb, Wob);

  // merged: projections (blocks 0..1535) + gate (blocks 1536..2047, 8 rows each)
  qkvg_gate<<<2048, 256, 0, stream>>>(xb, Wallb, Qbh, Kbh, Vtb, Gbh, qscale,
                                      x, gw1, gw2, gb2, EGK);

  chunk_prep<<<dim3(NCH, 8), 256, 0, stream>>>(Qbh, Kbh, EGK, qtb, ktb, khb, lamC);

  gla_pstate_mfma<<<dim3(4, 2, 128), 256, 0, stream>>>(khb, Vtb, Pjb);
  gla_sscan      <<<dim3(128, 8), 256, 0, stream>>>(Pjb, lamC, SjTb);
  gla_intra_mfma <<<dim3(2, NCH, 8), 256, 0, stream>>>(qtb, ktb, Vtb, SjTb, Obh);

  epilogue<<<NTOK, 256, 0, stream>>>(Obh, Gbh, gnw, Y2b);
  gemm_bf16<<<dim3(8, 32), 256, 0, stream>>>(Y2b, Wob, out, NTOK, 1024, 2048, 1.f);
}

// Round 24
// 258.541 us; speedup vs baseline: 1.3012x; 1.3012x over previous
//
#include <hip/hip_runtime.h>
#include <hip/hip_bf16.h>
#include <math.h>

#define NHEADS 4
#define DKH 256
#define DVH 512
#define SEQL 2048
#define NB 2
#define NTOK (NB*SEQL)     // 4096
#define DM 1024            // d_model
#define KDT 1024           // NHEADS*DKH
#define VDT 2048           // NHEADS*DVH
#define CHUNK 128
#define NCH (SEQL/CHUNK)   // 16

typedef unsigned short u16;
typedef unsigned int   u32;
typedef unsigned long long u64;
typedef __attribute__((ext_vector_type(8))) short bf16x8;
typedef __attribute__((ext_vector_type(4))) float f32x4;

__device__ inline u16 f2bf(float f) {
  __hip_bfloat16 h = __float2bfloat16(f);
  return *reinterpret_cast<u16*>(&h);
}
__device__ inline float bf2f(u16 u) {
  u32 x = ((u32)u) << 16;
  return __uint_as_float(x);
}

// async global->LDS, 16B/lane; LDS dest = wave-uniform base + lane*16 (linear).
__device__ __forceinline__ void gload16(const u16* g, u16* l) {
  __builtin_amdgcn_global_load_lds(
      (const __attribute__((address_space(1))) u32*)g,
      (__attribute__((address_space(3))) u32*)l,
      16, 0, 0);
}

__device__ inline float ls_exp(float z) {
  const float ls = (z >= 0.f) ? -log1pf(expf(-z)) : (z - log1pf(expf(z)));
  return expf(ls * 0.0625f);
}

// ---------------- fused prep: x->bf16 (blocks 0..2047) + 5 weight transposes ----
__global__ __launch_bounds__(256)
void prep_all(const float* __restrict__ x, u16* __restrict__ xb,
              const float* __restrict__ Wq, const float* __restrict__ Wk,
              const float* __restrict__ Wv, const float* __restrict__ Wg,
              const float* __restrict__ Wo, u16* __restrict__ Wall,
              u16* __restrict__ Wob)
{
  const int blk = blockIdx.x;
  if (blk < 2048) {                 // f2bf segment (no barrier)
    const int i = (blk * 256 + threadIdx.x) * 8;
    const float4 x0 = *(const float4*)&x[i];
    const float4 x1 = *(const float4*)&x[i + 4];
    int4 p;
    p.x = f2bf(x0.x) | ((u32)f2bf(x0.y) << 16);
    p.y = f2bf(x0.z) | ((u32)f2bf(x0.w) << 16);
    p.z = f2bf(x1.x) | ((u32)f2bf(x1.y) << 16);
    p.w = f2bf(x1.z) | ((u32)f2bf(x1.w) << 16);
    *(int4*)&xb[i] = p;
    return;
  }
  __shared__ float Ts[64][69];
  const int t = blk - 2048;
  const float* W; u16* Wt; int K, N, nx, ti;
  if (t < 256)       { W = Wq; Wt = Wall;                 K = 1024; N = 1024; nx = 16; ti = t; }
  else if (t < 512)  { W = Wk; Wt = Wall + 1024*1024;     K = 1024; N = 1024; nx = 16; ti = t - 256; }
  else if (t < 1024) { W = Wv; Wt = Wall + 2048*1024;     K = 1024; N = 2048; nx = 32; ti = t - 512; }
  else if (t < 1536) { W = Wg; Wt = Wall + 4096ull*1024;  K = 1024; N = 2048; nx = 32; ti = t - 1024; }
  else               { W = Wo; Wt = Wob;                  K = 2048; N = 1024; nx = 16; ti = t - 1536; }
  const int n0 = (ti % nx) * 64, k0 = (ti / nx) * 64;
  const int tx = threadIdx.x & 15, ty = threadIdx.x >> 4;
  #pragma unroll
  for (int r = 0; r < 4; ++r) {
    const int k = ty + r * 16;
    const float4 w4 = *(const float4*)&W[(size_t)(k0 + k) * N + n0 + tx * 4];
    Ts[tx*4 + 0][k] = w4.x;
    Ts[tx*4 + 1][k] = w4.y;
    Ts[tx*4 + 2][k] = w4.z;
    Ts[tx*4 + 3][k] = w4.w;
  }
  __syncthreads();
  #pragma unroll
  for (int r = 0; r < 4; ++r) {
    const int n = ty + r * 16;
    u64 pk = (u64)f2bf(Ts[n][tx*4 + 0]) | ((u64)f2bf(Ts[n][tx*4 + 1]) << 16)
           | ((u64)f2bf(Ts[n][tx*4 + 2]) << 32) | ((u64)f2bf(Ts[n][tx*4 + 3]) << 48);
    *(u64*)&Wt[(size_t)(n0 + n) * K + k0 + tx * 4] = pk;
  }
}

// ---------------- merged: projection GEMM (blocks 0..1535) + gate (1536..5631) --
// qkvg: 3-buffer counted-vmcnt pipeline (T4), swizzled LDS (rule #21).
// gate: per-row U = x@gk_w1 (block-local shfl reduce) -> EG; fills qkvg's tail.
__global__ __launch_bounds__(256)
void qkvg_gate(const u16* __restrict__ A, const u16* __restrict__ Wall,
               u16* __restrict__ Qh, u16* __restrict__ Kh,
               u16* __restrict__ Vt, u16* __restrict__ Gh, float qscale,
               const float* __restrict__ X, const float* __restrict__ W1,
               const float* __restrict__ W2, const float* __restrict__ b2,
               float* __restrict__ EGKo)
{
  __shared__ __align__(16) u16 As[3][128 * 32];   // 24KB (gate path aliases 320B)
  __shared__ __align__(16) u16 Bs[3][128 * 32];   // 24KB
  const int tid = threadIdx.x;

  if (blockIdx.x >= 1536) {
    // ---------------- gate path ----------------
    const int row = blockIdx.x - 1536;
    float* Us   = (float*)&As[0][0];      // 16 floats
    float* wred = Us + 16;                // 4x16 floats

    float p[16];
    #pragma unroll
    for (int n = 0; n < 16; ++n) p[n] = 0.f;
    const float4 x4 = *(const float4*)&X[(size_t)row * 1024 + tid * 4];
    const float xv[4] = {x4.x, x4.y, x4.z, x4.w};
    #pragma unroll
    for (int u = 0; u < 4; ++u) {
      const int k = tid * 4 + u;
      const float4 wA = *(const float4*)&W1[k*16 + 0];
      const float4 wB = *(const float4*)&W1[k*16 + 4];
      const float4 wC = *(const float4*)&W1[k*16 + 8];
      const float4 wD = *(const float4*)&W1[k*16 + 12];
      p[0]  += xv[u]*wA.x; p[1]  += xv[u]*wA.y; p[2]  += xv[u]*wA.z; p[3]  += xv[u]*wA.w;
      p[4]  += xv[u]*wB.x; p[5]  += xv[u]*wB.y; p[6]  += xv[u]*wB.z; p[7]  += xv[u]*wB.w;
      p[8]  += xv[u]*wC.x; p[9]  += xv[u]*wC.y; p[10] += xv[u]*wC.z; p[11] += xv[u]*wC.w;
      p[12] += xv[u]*wD.x; p[13] += xv[u]*wD.y; p[14] += xv[u]*wD.z; p[15] += xv[u]*wD.w;
    }
    #pragma unroll
    for (int n = 0; n < 16; ++n) {
      #pragma unroll
      for (int off = 32; off > 0; off >>= 1)
        p[n] += __shfl_down(p[n], off);
    }
    if ((tid & 63) == 0) {
      #pragma unroll
      for (int n = 0; n < 16; ++n) wred[(tid >> 6) * 16 + n] = p[n];
    }
    __syncthreads();
    if (tid < 16)
      Us[tid] = wred[tid] + wred[16 + tid] + wred[32 + tid] + wred[48 + tid];
    __syncthreads();

    const int d0 = tid << 2;
    float4 z = *(const float4*)&b2[d0];
    #pragma unroll
    for (int r = 0; r < 16; ++r) {
      const float u = Us[r];
      const float4 w4 = *(const float4*)&W2[r * 1024 + d0];
      z.x += u * w4.x; z.y += u * w4.y; z.z += u * w4.z; z.w += u * w4.w;
    }
    float4 e = make_float4(ls_exp(z.x), ls_exp(z.y), ls_exp(z.z), ls_exp(z.w));
    *(float4*)&EGKo[(size_t)row * 1024 + d0] = e;
    return;
  }

  // ---------------- qkvg path ----------------
  const int lane = tid & 63, wave = tid >> 6;
  const int wr = wave >> 1, wc = wave & 1;
  const int l15 = lane & 15, l4 = lane >> 4;
  const int bx = blockIdx.x % 48;
  const int bm = (blockIdx.x / 48) * 128, bn = bx * 128;

  f32x4 acc[4][4];
  #pragma unroll
  for (int i = 0; i < 4; ++i)
    #pragma unroll
    for (int j = 0; j < 4; ++j)
      acc[i][j] = (f32x4){0.f, 0.f, 0.f, 0.f};

  const int sRow = wave * 32 + (lane >> 2);
  const int sswz = (lane >> 3) & 3;                  // ((sRow>>1)&3)
  const int sCol = ((lane & 3) ^ sswz) * 8;          // swizzled global source col
  const int rswz = (l15 >> 1) & 3;
  const int ru = (l4 ^ rswz) * 8;                    // physical unit for frag reads
  const u16* Ag0 = &A   [(size_t)(bm + sRow) * DM + sCol];
  const u16* Ag1 = &A   [(size_t)(bm + sRow + 16) * DM + sCol];
  const u16* Bg0 = &Wall[(size_t)(bn + sRow) * DM + sCol];
  const u16* Bg1 = &Wall[(size_t)(bn + sRow + 16) * DM + sCol];
  const int lb0 = (wave * 32) * 32, lb1 = (wave * 32 + 16) * 32;

  // prologue: tiles 0 and 1 in flight (8 outstanding loads/wave)
  gload16(Ag0, &As[0][lb0]);
  gload16(Ag1, &As[0][lb1]);
  gload16(Bg0, &Bs[0][lb0]);
  gload16(Bg1, &Bs[0][lb1]);
  gload16(Ag0 + 32, &As[1][lb0]);
  gload16(Ag1 + 32, &As[1][lb1]);
  gload16(Bg0 + 32, &Bs[1][lb0]);
  gload16(Bg1 + 32, &Bs[1][lb1]);

  for (int k0 = 0; k0 < DM; k0 += 32) {
    const int cur = (k0 >> 5) % 3;
    // retire the oldest tile's 4 loads; keep the newest 4 in flight
    if (k0 + 64 < DM) asm volatile("s_waitcnt vmcnt(4)" ::: "memory");
    else              asm volatile("s_waitcnt vmcnt(0)" ::: "memory");
    __builtin_amdgcn_s_barrier();    // raw barrier: no vmcnt(0) drain
    if (k0 + 64 < DM) {              // issue tile k+2 (buffer read last in iter k-1)
      const int nxt = ((k0 >> 5) + 2) % 3;
      gload16(Ag0 + k0 + 64, &As[nxt][lb0]);
      gload16(Ag1 + k0 + 64, &As[nxt][lb1]);
      gload16(Bg0 + k0 + 64, &Bs[nxt][lb0]);
      gload16(Bg1 + k0 + 64, &Bs[nxt][lb1]);
    }
    bf16x8 af[4], bfv[4];
    #pragma unroll
    for (int mi = 0; mi < 4; ++mi)
      af[mi] = *(const bf16x8*)&As[cur][(wr*64 + mi*16 + l15) * 32 + ru];
    #pragma unroll
    for (int ni = 0; ni < 4; ++ni)
      bfv[ni] = *(const bf16x8*)&Bs[cur][(wc*64 + ni*16 + l15) * 32 + ru];
    #pragma unroll
    for (int mi = 0; mi < 4; ++mi)
      #pragma unroll
      for (int ni = 0; ni < 4; ++ni)
        acc[mi][ni] = __builtin_amdgcn_mfma_f32_16x16x32_bf16(af[mi], bfv[ni], acc[mi][ni], 0, 0, 0);
  }

  // per-segment bf16 epilogue (bx uniform per block)
  if (bx < 8) {              // Q cols [0,1024), scaled
    #pragma unroll
    for (int mi = 0; mi < 4; ++mi)
      #pragma unroll
      for (int ni = 0; ni < 4; ++ni) {
        const int col = bn + wc*64 + ni*16 + l15;
        #pragma unroll
        for (int r = 0; r < 4; ++r)
          Qh[(size_t)(bm + wr*64 + mi*16 + l4*4 + r) * 1024 + col] = f2bf(acc[mi][ni][r] * qscale);
      }
  } else if (bx < 16) {      // K cols [1024,2048)
    #pragma unroll
    for (int mi = 0; mi < 4; ++mi)
      #pragma unroll
      for (int ni = 0; ni < 4; ++ni) {
        const int col = bn - 1024 + wc*64 + ni*16 + l15;
        #pragma unroll
        for (int r = 0; r < 4; ++r)
          Kh[(size_t)(bm + wr*64 + mi*16 + l4*4 + r) * 1024 + col] = f2bf(acc[mi][ni][r]);
      }
  } else if (bx < 32) {      // V cols [2048,4096) -> transposed bf16 Vt
    #pragma unroll
    for (int mi = 0; mi < 4; ++mi) {
      const int row0 = bm + wr*64 + mi*16 + l4*4;   // token
      const int b = row0 >> 11, l = row0 & 2047;
      #pragma unroll
      for (int ni = 0; ni < 4; ++ni) {
        const int colV = bn - 2048 + wc*64 + ni*16 + l15;   // h*512 + dv
        const int h = colV >> 9, dv = colV & 511;
        u64 pk = (u64)f2bf(acc[mi][ni][0]) | ((u64)f2bf(acc[mi][ni][1]) << 16)
               | ((u64)f2bf(acc[mi][ni][2]) << 32) | ((u64)f2bf(acc[mi][ni][3]) << 48);
        *(u64*)&Vt[((size_t)((b*4 + h)*512 + dv)) * SEQL + l] = pk;
      }
    }
  } else {                   // G cols [4096,6144)
    #pragma unroll
    for (int mi = 0; mi < 4; ++mi)
      #pragma unroll
      for (int ni = 0; ni < 4; ++ni) {
        const int col = bn - 4096 + wc*64 + ni*16 + l15;
        #pragma unroll
        for (int r = 0; r < 4; ++r)
          Gh[(size_t)(bm + wr*64 + mi*16 + l4*4 + r) * 2048 + col] = f2bf(acc[mi][ni][r]);
      }
  }
}

// ---------------- generic bf16 GEMM: 3-buffer COUNTED-VMCNT pipeline, fp32 C ----
__global__ __launch_bounds__(256)
void gemm_bf16(const u16* __restrict__ A, const u16* __restrict__ Bt,
               float* __restrict__ C, int M, int N, int K, float scale)
{
  __shared__ __align__(16) u16 As[3][128 * 32];
  __shared__ __align__(16) u16 Bs[3][128 * 32];
  const int tid = threadIdx.x;
  const int lane = tid & 63, wave = tid >> 6;
  const int wr = wave >> 1, wc = wave & 1;
  const int l15 = lane & 15, l4 = lane >> 4;
  const int bm = blockIdx.y * 128, bn = blockIdx.x * 128;

  f32x4 acc[4][4];
  #pragma unroll
  for (int i = 0; i < 4; ++i)
    #pragma unroll
    for (int j = 0; j < 4; ++j)
      acc[i][j] = (f32x4){0.f, 0.f, 0.f, 0.f};

  const int sRow = wave * 32 + (lane >> 2);
  const int sswz = (lane >> 3) & 3;
  const int sCol = ((lane & 3) ^ sswz) * 8;
  const int rswz = (l15 >> 1) & 3;
  const int ru = (l4 ^ rswz) * 8;
  const u16* Ag0 = &A [(size_t)(bm + sRow) * K + sCol];
  const u16* Ag1 = &A [(size_t)(bm + sRow + 16) * K + sCol];
  const u16* Bg0 = &Bt[(size_t)(bn + sRow) * K + sCol];
  const u16* Bg1 = &Bt[(size_t)(bn + sRow + 16) * K + sCol];
  const int lb0 = (wave * 32) * 32, lb1 = (wave * 32 + 16) * 32;

  // prologue: tiles 0 and 1 in flight
  gload16(Ag0, &As[0][lb0]);
  gload16(Ag1, &As[0][lb1]);
  gload16(Bg0, &Bs[0][lb0]);
  gload16(Bg1, &Bs[0][lb1]);
  gload16(Ag0 + 32, &As[1][lb0]);
  gload16(Ag1 + 32, &As[1][lb1]);
  gload16(Bg0 + 32, &Bs[1][lb0]);
  gload16(Bg1 + 32, &Bs[1][lb1]);

  for (int k0 = 0; k0 < K; k0 += 32) {
    const int cur = (k0 >> 5) % 3;
    if (k0 + 64 < K) asm volatile("s_waitcnt vmcnt(4)" ::: "memory");
    else             asm volatile("s_waitcnt vmcnt(0)" ::: "memory");
    __builtin_amdgcn_s_barrier();
    if (k0 + 64 < K) {
      const int nxt = ((k0 >> 5) + 2) % 3;
      gload16(Ag0 + k0 + 64, &As[nxt][lb0]);
      gload16(Ag1 + k0 + 64, &As[nxt][lb1]);
      gload16(Bg0 + k0 + 64, &Bs[nxt][lb0]);
      gload16(Bg1 + k0 + 64, &Bs[nxt][lb1]);
    }
    bf16x8 af[4], bfv[4];
    #pragma unroll
    for (int mi = 0; mi < 4; ++mi)
      af[mi] = *(const bf16x8*)&As[cur][(wr*64 + mi*16 + l15) * 32 + ru];
    #pragma unroll
    for (int ni = 0; ni < 4; ++ni)
      bfv[ni] = *(const bf16x8*)&Bs[cur][(wc*64 + ni*16 + l15) * 32 + ru];
    #pragma unroll
    for (int mi = 0; mi < 4; ++mi)
      #pragma unroll
      for (int ni = 0; ni < 4; ++ni)
        acc[mi][ni] = __builtin_amdgcn_mfma_f32_16x16x32_bf16(af[mi], bfv[ni], acc[mi][ni], 0, 0, 0);
  }

  #pragma unroll
  for (int mi = 0; mi < 4; ++mi)
    #pragma unroll
    for (int ni = 0; ni < 4; ++ni) {
      const int col = bn + wc*64 + ni*16 + l15;
      #pragma unroll
      for (int r = 0; r < 4; ++r) {
        const int row = bm + wr*64 + mi*16 + l4*4 + r;
        C[(size_t)row * N + col] = acc[mi][ni][r] * scale;
      }
    }
}

// ---------------- chunk_prep (bf16 in): qt=q*Lam, kt=k/Lam, kh=kt*LamC ----------
__global__ __launch_bounds__(256)
void chunk_prep(const u16* __restrict__ Qh, const u16* __restrict__ Kh,
                const float* __restrict__ EG, u16* __restrict__ qtb,
                u16* __restrict__ ktb, u16* __restrict__ khb,
                float* __restrict__ lamC)
{
  const int j = blockIdx.x;
  const int bh = blockIdx.y;
  const int b = bh >> 2, h = bh & 3;
  const int tid = threadIdx.x;   // dk lane
  const size_t base = ((size_t)(b * SEQL + j * CHUNK)) * KDT + h * DKH + tid;
  float cum = 1.f;
  for (int t = 0; t < CHUNK; t += 4) {
    const size_t i0 = base + (size_t)t * KDT;
    float d[4], q[4], k[4];
    #pragma unroll
    for (int u = 0; u < 4; ++u) {
      d[u] = EG[i0 + (size_t)u * KDT];
      q[u] = bf2f(Qh[i0 + (size_t)u * KDT]);
      k[u] = bf2f(Kh[i0 + (size_t)u * KDT]);
    }
    #pragma unroll
    for (int u = 0; u < 4; ++u) {
      cum *= d[u];
      qtb[i0 + (size_t)u * KDT] = f2bf(q[u] * cum);
      ktb[i0 + (size_t)u * KDT] = f2bf(k[u] / cum);
    }
  }
  lamC[(bh * NCH + j) * 256 + tid] = cum;
  for (int t = 0; t < CHUNK; t += 4) {
    const size_t i0 = base + (size_t)t * KDT;
    u16 kt4[4];
    #pragma unroll
    for (int u = 0; u < 4; ++u) kt4[u] = ktb[i0 + (size_t)u * KDT];
    #pragma unroll
    for (int u = 0; u < 4; ++u)
      khb[i0 + (size_t)u * KDT] = f2bf(bf2f(kt4[u]) * cum);
  }
}

// ---------------- gla_pstate_mfma: P^T[dv][dk] = Vt_j @ kh_j (MFMA), bf16 P out -
__global__ __launch_bounds__(256)
void gla_pstate_mfma(const u16* __restrict__ kh, const u16* __restrict__ Vt,
                     u16* __restrict__ P)
{
  const int mb = blockIdx.x, nb = blockIdx.y, jc = blockIdx.z;
  const int bh = jc >> 4, j = jc & 15;
  const int b = bh >> 2, h = bh & 3;
  const int tid = threadIdx.x;
  const int lane = tid & 63, wave = tid >> 6;
  const int wr = wave >> 1, wc = wave & 1;
  const int l15 = lane & 15, l4 = lane >> 4;
  const int tok0 = b * SEQL + j * CHUNK;

  __shared__ __align__(16) u16 Al[128 * 40];   // Vt [dv][t]
  __shared__ __align__(16) u16 Blt[128 * 40];  // kh^T [dk][t]

  f32x4 acc[4][4];
  #pragma unroll
  for (int i = 0; i < 4; ++i)
    #pragma unroll
    for (int jj = 0; jj < 4; ++jj) acc[i][jj] = (f32x4){0.f,0.f,0.f,0.f};

  for (int kt0 = 0; kt0 < CHUNK; kt0 += 32) {
    {
      const int srow = tid >> 2, scol = (tid & 3) * 8;
      *(int4*)&Al[(srow)    * 40 + scol] =
        *(const int4*)&Vt[((size_t)(bh*512 + mb*128 + srow))    * SEQL + j*CHUNK + kt0 + scol];
      *(int4*)&Al[(64+srow) * 40 + scol] =
        *(const int4*)&Vt[((size_t)(bh*512 + mb*128 + 64+srow)) * SEQL + j*CHUNK + kt0 + scol];
    }
    {
      const int t = tid & 31;
      #pragma unroll
      for (int i = 0; i < 2; ++i) {
        const int dkg = (tid >> 5) * 16 + i * 8;
        int4 v = *(const int4*)&kh[(size_t)(tok0 + kt0 + t) * KDT + h*DKH + nb*128 + dkg];
        const u16* pv = (const u16*)&v;
        #pragma unroll
        for (int u = 0; u < 8; ++u) Blt[(dkg + u)*40 + t] = pv[u];
      }
    }
    __syncthreads();
    bf16x8 af[4], bv[4];
    #pragma unroll
    for (int mi = 0; mi < 4; ++mi)
      af[mi] = *(const bf16x8*)&Al[(wr*64 + mi*16 + l15)*40 + l4*8];
    #pragma unroll
    for (int ni = 0; ni < 4; ++ni)
      bv[ni] = *(const bf16x8*)&Blt[(wc*64 + ni*16 + l15)*40 + l4*8];
    #pragma unroll
    for (int mi = 0; mi < 4; ++mi)
      #pragma unroll
      for (int ni = 0; ni < 4; ++ni)
        acc[mi][ni] = __builtin_amdgcn_mfma_f32_16x16x32_bf16(af[mi], bv[ni], acc[mi][ni], 0, 0, 0);
    __syncthreads();
  }

  #pragma unroll
  for (int mi = 0; mi < 4; ++mi)
    #pragma unroll
    for (int ni = 0; ni < 4; ++ni) {
      const int col = nb*128 + wc*64 + ni*16 + l15;   // dk
      #pragma unroll
      for (int r = 0; r < 4; ++r) {
        const int row = mb*128 + wr*64 + mi*16 + l4*4 + r;  // dv
        P[(size_t)jc * 131072 + (size_t)row * 256 + col] = f2bf(acc[mi][ni][r]);
      }
    }
}

// ---------------- gla_sscan: S^T recurrence, bf16 P in, bf16 SjT out ------------
__global__ __launch_bounds__(256)
void gla_sscan(const u16* __restrict__ P, const float* __restrict__ lamC,
               u16* __restrict__ SjT)
{
  const int bh = blockIdx.y;
  const int e0 = blockIdx.x * 1024 + threadIdx.x * 4;
  const int dv = e0 >> 8, dk = e0 & 255;
  float4 S = make_float4(0.f, 0.f, 0.f, 0.f);
  for (int j = 0; j < NCH; ++j) {
    const size_t cb = (size_t)(bh * NCH + j);
    const float4 lam = *(const float4*)&lamC[cb * 256 + dk];
    const size_t idx = cb * 131072 + (size_t)dv * 256 + dk;
    const u64 pkin = *(const u64*)&P[idx];
    const float t0 = bf2f((u16)(pkin       & 0xffff));
    const float t1 = bf2f((u16)((pkin>>16) & 0xffff));
    const float t2 = bf2f((u16)((pkin>>32) & 0xffff));
    const float t3 = bf2f((u16)((pkin>>48) & 0xffff));
    u64 pk = (u64)f2bf(S.x) | ((u64)f2bf(S.y) << 16)
           | ((u64)f2bf(S.z) << 32) | ((u64)f2bf(S.w) << 48);
    *(u64*)&SjT[idx] = pk;
    S.x = lam.x * S.x + t0;
    S.y = lam.y * S.y + t1;
    S.z = lam.z * S.z + t2;
    S.w = lam.w * S.w + t3;
  }
}

// ---------------- fused gla core: O(bf16) = tril(qt@kt^T)@V + qt@S_j ------------
__global__ __launch_bounds__(256)
void gla_intra_mfma(const u16* __restrict__ qt, const u16* __restrict__ kt,
                    const u16* __restrict__ Vt, const u16* __restrict__ SjT,
                    u16* __restrict__ O)
{
  const int half = blockIdx.x;
  const int j    = blockIdx.y;
  const int bh   = blockIdx.z;
  const int b = bh >> 2, h = bh & 3;
  const int tid = threadIdx.x;
  const int lane = tid & 63, wave = tid >> 6;
  const int wr = wave >> 1, wc = wave & 1;
  const int l15 = lane & 15, l4 = lane >> 4;
  const int tok0 = b * SEQL + j * CHUNK;

  __shared__ __align__(16) u16 Pl[128 * 136];    // masked P bf16 [t][s]
  __shared__ __align__(16) u16 stg[128 * 136];   // union staging (17408 u16)
  u16* As  = stg;                  // [128][40] qt
  u16* Bs0 = stg + 128 * 40;       // [128][40] kt / SjT-dt0
  u16* Bs1 = stg + 2 * 128 * 40;   // [128][40] SjT-dt1

  const size_t qkBase = (size_t)tok0 * KDT + h * DKH;
  const size_t sjBase = (size_t)(bh * NCH + j) * 131072;

  const int srow = tid >> 2;
  const int scol = (tid & 3) * 8;

  // ---- QK^T (K=256), reg prefetch ----
  f32x4 acc[4][4];
  #pragma unroll
  for (int i = 0; i < 4; ++i)
    #pragma unroll
    for (int jj = 0; jj < 4; ++jj) acc[i][jj] = (f32x4){0.f,0.f,0.f,0.f};

  int4 ra0 = *(const int4*)&qt[qkBase + (size_t)srow      * KDT + scol];
  int4 ra1 = *(const int4*)&qt[qkBase + (size_t)(64+srow) * KDT + scol];
  int4 rb0 = *(const int4*)&kt[qkBase + (size_t)srow      * KDT + scol];
  int4 rb1 = *(const int4*)&kt[qkBase + (size_t)(64+srow) * KDT + scol];

  for (int dk0 = 0; dk0 < DKH; dk0 += 32) {
    __syncthreads();
    *(int4*)&As [(srow)    * 40 + scol] = ra0;
    *(int4*)&As [(64+srow) * 40 + scol] = ra1;
    *(int4*)&Bs0[(srow)    * 40 + scol] = rb0;
    *(int4*)&Bs0[(64+srow) * 40 + scol] = rb1;
    __syncthreads();
    if (dk0 + 32 < DKH) {
      ra0 = *(const int4*)&qt[qkBase + (size_t)srow      * KDT + dk0 + 32 + scol];
      ra1 = *(const int4*)&qt[qkBase + (size_t)(64+srow) * KDT + dk0 + 32 + scol];
      rb0 = *(const int4*)&kt[qkBase + (size_t)srow      * KDT + dk0 + 32 + scol];
      rb1 = *(const int4*)&kt[qkBase + (size_t)(64+srow) * KDT + dk0 + 32 + scol];
    }
    if (wave != 1) {   // wave 1 = (wr0,wc1): rows 0-63 x cols 64-127, all masked
      bf16x8 af[4], bv[4];
      #pragma unroll
      for (int mi = 0; mi < 4; ++mi)
        af[mi] = *(const bf16x8*)&As[(wr*64 + mi*16 + l15) * 40 + l4*8];
      #pragma unroll
      for (int ni = 0; ni < 4; ++ni)
        bv[ni] = *(const bf16x8*)&Bs0[(wc*64 + ni*16 + l15) * 40 + l4*8];
      #pragma unroll
      for (int mi = 0; mi < 4; ++mi)
        #pragma unroll
        for (int ni = 0; ni < 4; ++ni)
          acc[mi][ni] = __builtin_amdgcn_mfma_f32_16x16x32_bf16(af[mi], bv[ni], acc[mi][ni], 0, 0, 0);
    }
  }
  __syncthreads();

  // mask -> Pl bf16 [t][s]  (wave 1 writes zeros)
  #pragma unroll
  for (int mi = 0; mi < 4; ++mi)
    #pragma unroll
    for (int ni = 0; ni < 4; ++ni) {
      const int s = wc*64 + ni*16 + l15;
      #pragma unroll
      for (int r = 0; r < 4; ++r) {
        const int t = wr*64 + mi*16 + l4*4 + r;
        Pl[t*136 + s] = (s <= t) ? f2bf(acc[mi][ni][r]) : (u16)0;
      }
    }
  __syncthreads();

  // ---- inter for BOTH dt tiles in one k-loop: qt staged once ----
  const int dv0 = half*256;
  const int dv1 = half*256 + 128;
  f32x4 acc2[2][4][4];
  #pragma unroll
  for (int d = 0; d < 2; ++d)
    #pragma unroll
    for (int i = 0; i < 4; ++i)
      #pragma unroll
      for (int jj = 0; jj < 4; ++jj) acc2[d][i][jj] = (f32x4){0.f,0.f,0.f,0.f};

  int4 ia0 = *(const int4*)&qt [qkBase + (size_t)srow      * KDT + scol];
  int4 ia1 = *(const int4*)&qt [qkBase + (size_t)(64+srow) * KDT + scol];
  int4 ib0 = *(const int4*)&SjT[sjBase + (size_t)(dv0 + srow)      * 256 + scol];
  int4 ib1 = *(const int4*)&SjT[sjBase + (size_t)(dv0 + 64 + srow) * 256 + scol];
  int4 ic0 = *(const int4*)&SjT[sjBase + (size_t)(dv1 + srow)      * 256 + scol];
  int4 ic1 = *(const int4*)&SjT[sjBase + (size_t)(dv1 + 64 + srow) * 256 + scol];

  for (int k0 = 0; k0 < DKH; k0 += 32) {
    __syncthreads();
    *(int4*)&As [(srow)    * 40 + scol] = ia0;
    *(int4*)&As [(64+srow) * 40 + scol] = ia1;
    *(int4*)&Bs0[(srow)    * 40 + scol] = ib0;
    *(int4*)&Bs0[(64+srow) * 40 + scol] = ib1;
    *(int4*)&Bs1[(srow)    * 40 + scol] = ic0;
    *(int4*)&Bs1[(64+srow) * 40 + scol] = ic1;
    __syncthreads();
    if (k0 + 32 < DKH) {
      ia0 = *(const int4*)&qt [qkBase + (size_t)srow      * KDT + k0 + 32 + scol];
      ia1 = *(const int4*)&qt [qkBase + (size_t)(64+srow) * KDT + k0 + 32 + scol];
      ib0 = *(const int4*)&SjT[sjBase + (size_t)(dv0 + srow)      * 256 + k0 + 32 + scol];
      ib1 = *(const int4*)&SjT[sjBase + (size_t)(dv0 + 64 + srow) * 256 + k0 + 32 + scol];
      ic0 = *(const int4*)&SjT[sjBase + (size_t)(dv1 + srow)      * 256 + k0 + 32 + scol];
      ic1 = *(const int4*)&SjT[sjBase + (size_t)(dv1 + 64 + srow) * 256 + k0 + 32 + scol];
    }
    bf16x8 af[4], bv0[4], bv1[4];
    #pragma unroll
    for (int mi = 0; mi < 4; ++mi)
      af[mi] = *(const bf16x8*)&As[(wr*64 + mi*16 + l15) * 40 + l4*8];
    #pragma unroll
    for (int ni = 0; ni < 4; ++ni) {
      bv0[ni] = *(const bf16x8*)&Bs0[(wc*64 + ni*16 + l15) * 40 + l4*8];
      bv1[ni] = *(const bf16x8*)&Bs1[(wc*64 + ni*16 + l15) * 40 + l4*8];
    }
    #pragma unroll
    for (int mi = 0; mi < 4; ++mi)
      #pragma unroll
      for (int ni = 0; ni < 4; ++ni) {
        acc2[0][mi][ni] = __builtin_amdgcn_mfma_f32_16x16x32_bf16(af[mi], bv0[ni], acc2[0][mi][ni], 0, 0, 0);
        acc2[1][mi][ni] = __builtin_amdgcn_mfma_f32_16x16x32_bf16(af[mi], bv1[ni], acc2[1][mi][ni], 0, 0, 0);
      }
  }
  __syncthreads();

  // ---- PV per dt: stage V tile then 16 MFMA, single bf16 O write ----
  for (int dt = 0; dt < 2; ++dt) {
    const int dvBase = half*256 + dt*128;
    #pragma unroll
    for (int i = 0; i < 8; ++i) {
      const int row = i*16 + (tid >> 4);
      const int col8 = (tid & 15) * 8;
      *(int4*)&stg[row*136 + col8] =
        *(const int4*)&Vt[((size_t)(bh*512 + dvBase + row)) * SEQL + j*CHUNK + col8];
    }
    __syncthreads();
    #pragma unroll
    for (int ks = 0; ks < 4; ++ks) {
      bf16x8 af2[4], bv2[4];
      #pragma unroll
      for (int mi = 0; mi < 4; ++mi)
        af2[mi] = *(const bf16x8*)&Pl[(wr*64 + mi*16 + l15)*136 + ks*32 + l4*8];
      #pragma unroll
      for (int ni = 0; ni < 4; ++ni)
        bv2[ni] = *(const bf16x8*)&stg[(wc*64 + ni*16 + l15)*136 + ks*32 + l4*8];
      #pragma unroll
      for (int mi = 0; mi < 4; ++mi)
        #pragma unroll
        for (int ni = 0; ni < 4; ++ni)
          acc2[dt][mi][ni] = __builtin_amdgcn_mfma_f32_16x16x32_bf16(af2[mi], bv2[ni], acc2[dt][mi][ni], 0, 0, 0);
    }
    #pragma unroll
    for (int mi = 0; mi < 4; ++mi)
      #pragma unroll
      for (int ni = 0; ni < 4; ++ni) {
        const int col = h*DVH + dvBase + wc*64 + ni*16 + l15;
        #pragma unroll
        for (int r = 0; r < 4; ++r) {
          const int row = tok0 + wr*64 + mi*16 + l4*4 + r;
          O[(size_t)row * VDT + col] = f2bf(acc2[dt][mi][ni][r]);
        }
      }
    __syncthreads();
  }
}

// ---------------- epilogue: Y(bf16) = RMSNorm(o)*w * silu(g), bf16 O,G ----------
__global__ __launch_bounds__(256)
void epilogue(const u16* __restrict__ O, const u16* __restrict__ G,
              const float* __restrict__ w, u16* __restrict__ Y)
{
  const int row = blockIdx.x;
  const int tid = threadIdx.x;
  __shared__ float sred[4];
  for (int h = 0; h < NHEADS; ++h) {
    const size_t base = (size_t)row * VDT + h * DVH;
    const u32 o2p = *(const u32*)&O[base + tid * 2];
    const float ox = bf2f((u16)(o2p & 0xffff));
    const float oy = bf2f((u16)(o2p >> 16));
    float ss = ox * ox + oy * oy;
    #pragma unroll
    for (int off = 32; off > 0; off >>= 1) ss += __shfl_down(ss, off);
    if ((tid & 63) == 0) sred[tid >> 6] = ss;
    __syncthreads();
    const float tot = sred[0] + sred[1] + sred[2] + sred[3];
    const float rs = rsqrtf(tot * (1.f / DVH) + 1e-5f);
    const u32 g2p = *(const u32*)&G[base + tid * 2];
    const float gx = bf2f((u16)(g2p & 0xffff));
    const float gy = bf2f((u16)(g2p >> 16));
    const float2 w2 = *(const float2*)&w[tid * 2];
    const float y0 = ox * rs * w2.x * gx / (1.f + expf(-gx));
    const float y1 = oy * rs * w2.y * gy / (1.f + expf(-gy));
    const u32 pk = (u32)f2bf(y0) | ((u32)f2bf(y1) << 16);
    *(u32*)&Y[base + tid * 2] = pk;
    __syncthreads();
  }
}

extern "C" void kernel_launch(void* const* d_in, const int* in_sizes, int n_in,
                              void* d_out, int out_size, void* d_ws, size_t ws_size,
                              hipStream_t stream)
{
  const float* x    = (const float*)d_in[0];
  const float* Wq   = (const float*)d_in[1];
  const float* Wk   = (const float*)d_in[2];
  const float* Wv   = (const float*)d_in[3];
  const float* Wg   = (const float*)d_in[4];
  const float* gw1  = (const float*)d_in[5];
  const float* gw2  = (const float*)d_in[6];
  const float* gb2  = (const float*)d_in[7];
  const float* gnw  = (const float*)d_in[8];
  const float* Wo   = (const float*)d_in[9];
  float* out = (float*)d_out;

  // ---- workspace layout (float-slot offsets; liveness documented) ----
  float* ws = (float*)d_ws;
  const size_t M = 1024ull * 1024ull;
  u16*   Qbh  = (u16*)(ws);         // [0,2M)   bf16 Q; dead after chunk_prep
  u16*   Kbh  = (u16*)(ws + 2*M);   // [2M,4M)  bf16 K; dead after chunk_prep
  float* EGK  = ws + 4*M;           // [4M,8M)  fp32 decay; dead after chunk_prep
  u16*   Vtb  = (u16*)(ws + 8*M);   // [8M,12M) bf16 Vt; LIVE until gla_intra done
  u16*   qtb  = (u16*)(ws + 12*M);  // [12M,14M) live until gla_intra
  u16*   ktb  = (u16*)(ws + 14*M);  // [14M,16M) live until gla_intra
  u16*   Gbh  = (u16*)(ws + 16*M);  // [16M,20M) bf16 G; live until epilogue
  u16*   Obh  = (u16*)(ws + 20*M);  // [20M,24M) bf16 O
  u16*   Pjb  = (u16*)(ws + 28*M);  // [28M,36M) bf16 P^T; dead after sscan
  float* lamC = ws + 44*M;          // [44M, +32K)
  u16*   khb  = (u16*)(ws + 45*M);  // [45M,47M) dead after gla_pstate
  u16*   xb   = (u16*)(ws + 47*M);  // [47M,49M) dead after qkvg_gate
  u16*   Wallb= (u16*)(ws + 49*M);  // [49M,52M) dead after qkvg_gate
  u16*   Wob  = (u16*)(ws + 52*M);  // [52M,53M) live until final gemm
  u16*   SjTb = (u16*)(ws + 53*M);  // [53M,61M) 32MB; fresh region (no aliasing)
  u16*   Y2b  = (u16*)(ws);         // [0,4M) reuses Qbh+Kbh after chunk_prep

  const float qscale = 0.0625f;     // DK^-0.5

  prep_all<<<4096, 256, 0, stream>>>(x, xb, Wq, Wk, Wv, Wg, Wo, Wallb, Wob);

  // merged: projections (blocks 0..1535) + gate (blocks 1536..5631)
  qkvg_gate<<<5632, 256, 0, stream>>>(xb, Wallb, Qbh, Kbh, Vtb, Gbh, qscale,
                                      x, gw1, gw2, gb2, EGK);

  chunk_prep<<<dim3(NCH, 8), 256, 0, stream>>>(Qbh, Kbh, EGK, qtb, ktb, khb, lamC);

  gla_pstate_mfma<<<dim3(4, 2, 128), 256, 0, stream>>>(khb, Vtb, Pjb);
  gla_sscan      <<<dim3(128, 8), 256, 0, stream>>>(Pjb, lamC, SjTb);
  gla_intra_mfma <<<dim3(2, NCH, 8), 256, 0, stream>>>(qtb, ktb, Vtb, SjTb, Obh);

  epilogue<<<NTOK, 256, 0, stream>>>(Obh, Gbh, gnw, Y2b);
  gemm_bf16<<<dim3(8, 32), 256, 0, stream>>>(Y2b, Wob, out, NTOK, 1024, 2048, 1.f);
}